// Round 7
// baseline (582.800 us; speedup 1.0000x reference)
//
#include <hip/hip_runtime.h>

#define B_    8192
#define N_    29
#define F_    147
#define DC    429
#define D_    128
#define ROWS  (B_*N_)
#define EPSBN 1e-5f

#define UTSTR   4096                        /* shorts per b */
#define RS_SH   3712                        /* short offset of rowstats */

/* ws layout in float units */
#define X3_OFF   16777216                   /* fp32 B_*128 */
#define ACC_OFF  (X3_OFF + B_*D_)
#define BN1_OFF  (ACC_OFF)                  /* 32*29*2 */
#define BN2_OFF  (ACC_OFF + 1856)
#define BN3_OFF  (ACC_OFF + 3712)           /* 32*128*2 */
#define FIN_OFF  (ACC_OFF + 11904)
#define CSW_OFF  (FIN_OFF + 384)
#define V_OFF    (FIN_OFF + 512)
#define V1_OFF   (FIN_OFF + 640)
#define CSWP_OFF (FIN_OFF + 768)
#define IMG_OFF  (FIN_OFF + 1024)           /* bf16 Wg image: 128*448 shorts */
#define WPI_OFF  (IMG_OFF + 28672)          /* bf16 Wp^T image */
#define WM1I_OFF (WPI_OFF + 8192)           /* bf16 Wm1^T image */

typedef __bf16 bf16x8 __attribute__((ext_vector_type(8)));
typedef float  f32x4  __attribute__((ext_vector_type(4)));

__device__ __forceinline__ unsigned short f2bf(float f) {
  unsigned int u = __float_as_uint(f);
  u += 0x7fffu + ((u >> 16) & 1u);
  return (unsigned short)(u >> 16);
}
__device__ __forceinline__ float bf2f(unsigned u16) {
  return __uint_as_float(u16 << 16);
}

#define TSTR 456
#define UTILS 34
#define ATSTR 136

/* K0a: Wg image + colsum (blocks 0..15); Wp^T image + colsum (16); Wm1^T image (17). */
__global__ void k0a_img(const float* __restrict__ Wg, const float* __restrict__ Wp,
                        const float* __restrict__ Wm1, float* __restrict__ ws)
{
  const int tid = threadIdx.x;
  if (blockIdx.x < 16) {
    __shared__ float cs_l[8];
    const int kb = blockIdx.x * 8;
    if (tid < 8) cs_l[tid] = 0.f;
    __syncthreads();
    unsigned short* img = (unsigned short*)(ws + IMG_OFF);
    for (int i = tid; i < 8*448; i += 256) {
      int kk = i / 448, dk = i - kk*448;
      int k = kb + kk;
      int d;
      if      (dk < 145)  d = dk;
      else if (dk == 145) d = -1;
      else if (dk < 289)  d = dk - 1;
      else if (dk == 289) d = -1;
      else if (dk < 431)  d = dk - 2;
      else                d = -1;
      float v = (d >= 0) ? Wg[(size_t)d*D_ + k] : 0.f;
      img[(size_t)k*448 + dk] = f2bf(v);
      if (d >= 0) atomicAdd(&cs_l[kk], v);
    }
    __syncthreads();
    if (tid < 8) ws[CSW_OFF + kb + tid] = cs_l[tid];
  } else if (blockIdx.x == 16) {
    unsigned short* wpi = (unsigned short*)(ws + WPI_OFF);
    for (int i = tid; i < 16384; i += 256) {
      int k = i >> 7, c = i & 127;
      wpi[c*128 + k] = f2bf(Wp[k*128 + c]);
    }
    if (tid < 128) {
      float s = 0.f;
      for (int k = 0; k < 128; ++k) s += Wp[k*128 + tid];
      ws[CSWP_OFF + tid] = s;
    }
  } else {
    unsigned short* wmi = (unsigned short*)(ws + WM1I_OFF);
    for (int i = tid; i < 16384; i += 256) {
      int k = i >> 7, c = i & 127;
      wmi[c*128 + k] = f2bf(Wm1[k*128 + c]);
    }
  }
}

/* K0b: v = sum_h hw[h]*normalize(cent[h]); V1 = sum(v). */
__global__ void k0b_cent(const float* __restrict__ cent, const float* __restrict__ hw,
                         float* __restrict__ ws)
{
  __shared__ float sq[128];
  __shared__ float nrm;
  const int tid = threadIdx.x;
  float vk = 0.f;
  for (int h = 0; h < 4; ++h) {
    float c = cent[h*D_ + tid];
    sq[tid] = c*c;
    __syncthreads();
    if (tid == 0) { float s=0.f; for (int j=0;j<128;++j) s+=sq[j]; nrm = sqrtf(s)+1e-8f; }
    __syncthreads();
    vk += hw[h] * c / nrm;
    __syncthreads();
  }
  ws[V_OFF + tid] = vk;
  sq[tid] = vk;
  __syncthreads();
  if (tid == 0) { float s=0.f; for (int j=0;j<128;++j) s+=sq[j]; ws[V1_OFF] = s; }
}

/* K1: 2 b per block (unchanged from r6). */
__global__ __launch_bounds__(512, 2) void k1_conv_gemm(
    const float* __restrict__ X,
    const float* __restrict__ wc1, const float* __restrict__ bc1,
    const float* __restrict__ wc2, const float* __restrict__ bc2,
    const float* __restrict__ wc3, const float* __restrict__ bc3,
    const float* __restrict__ acnn, float* __restrict__ ws)
{
  __shared__ __align__(16) unsigned short t_s[64*TSTR];
  const int tid = threadIdx.x;
  const int b0 = blockIdx.x * 2;

  for (int i = tid; i < 2*3*448; i += 512) {
    int bbz = i / (3*448), rem = i - bbz*(3*448);
    int r = rem / 448, c = rem - r*448;
    t_s[(bbz*32 + 29 + r)*TSTR + c] = 0;
  }
  for (int i = tid; i < 58*19; i += 512) {
    int rr = i / 19, j = i - rr*19;
    int bbz = (rr >= 29), n = rr - bbz*29;
    int col = (j == 0) ? 145 : ((j == 1) ? 289 : (429 + j));
    t_s[(bbz*32 + n)*TSTR + col] = 0;
  }

  const float c10 = wc1[0], c11 = wc1[1], c12 = wc1[2], b1 = bc1[0];
  const float c20 = wc2[0], c21 = wc2[1], c22 = wc2[2], c23 = wc2[3], c24 = wc2[4], b2 = bc2[0];
  const float c30 = wc3[0], c31 = wc3[1], c32 = wc3[2], c33 = wc3[3], c34 = wc3[4],
              c35 = wc3[5], c36 = wc3[6], b3 = bc3[0];
  const float ap = acnn[0];

  {
    const int r = tid >> 3, q = tid & 7;
    const int bb = r >> 5, n = r & 31;
    const bool act = (n < 29);
    const int f0 = q * 19;
    const int nld = act ? n : 28;
    const float* xr = X + (size_t)((b0 + bb)*N_ + nld) * F_;
    float xv[25];
    #pragma unroll
    for (int i = 0; i < 25; ++i) xv[i] = xr[min(f0 + i, 146)];

    float s1 = 0.f, s2 = 0.f;
    unsigned short* tr = t_s + (bb*32 + n)*TSTR;
    if (act) {
      if (q < 7) {
        #pragma unroll
        for (int i = 0; i < 19; ++i) {
          float v1 = fmaf(xv[i],c10, fmaf(xv[i+1],c11, fmaf(xv[i+2],c12, b1)));
          v1 = (v1 >= 0.f) ? v1 : ap*v1;
          s1 += v1; s2 = fmaf(v1, v1, s2);
          tr[f0 + i] = f2bf(v1);
          float v2 = fmaf(xv[i],c20, fmaf(xv[i+1],c21, fmaf(xv[i+2],c22, fmaf(xv[i+3],c23, fmaf(xv[i+4],c24, b2)))));
          v2 = (v2 >= 0.f) ? v2 : ap*v2;
          s1 += v2; s2 = fmaf(v2, v2, s2);
          tr[146 + f0 + i] = f2bf(v2);
          float v3 = fmaf(xv[i],c30, fmaf(xv[i+1],c31, fmaf(xv[i+2],c32, fmaf(xv[i+3],c33, fmaf(xv[i+4],c34, fmaf(xv[i+5],c35, fmaf(xv[i+6],c36, b3)))))));
          v3 = (v3 >= 0.f) ? v3 : ap*v3;
          s1 += v3; s2 = fmaf(v3, v3, s2);
          tr[290 + f0 + i] = f2bf(v3);
        }
      } else {
        #pragma unroll
        for (int i = 0; i < 12; ++i) {
          float v1 = fmaf(xv[i],c10, fmaf(xv[i+1],c11, fmaf(xv[i+2],c12, b1)));
          v1 = (v1 >= 0.f) ? v1 : ap*v1;
          s1 += v1; s2 = fmaf(v1, v1, s2);
          tr[133 + i] = f2bf(v1);
        }
        #pragma unroll
        for (int i = 0; i < 10; ++i) {
          float v2 = fmaf(xv[i],c20, fmaf(xv[i+1],c21, fmaf(xv[i+2],c22, fmaf(xv[i+3],c23, fmaf(xv[i+4],c24, b2)))));
          v2 = (v2 >= 0.f) ? v2 : ap*v2;
          s1 += v2; s2 = fmaf(v2, v2, s2);
          tr[279 + i] = f2bf(v2);
        }
        #pragma unroll
        for (int i = 0; i < 8; ++i) {
          float v3 = fmaf(xv[i],c30, fmaf(xv[i+1],c31, fmaf(xv[i+2],c32, fmaf(xv[i+3],c33, fmaf(xv[i+4],c34, fmaf(xv[i+5],c35, fmaf(xv[i+6],c36, b3)))))));
          v3 = (v3 >= 0.f) ? v3 : ap*v3;
          s1 += v3; s2 = fmaf(v3, v3, s2);
          tr[423 + i] = f2bf(v3);
        }
      }
    }
    #pragma unroll
    for (int off = 4; off >= 1; off >>= 1) {
      s1 += __shfl_xor(s1, off);
      s2 += __shfl_xor(s2, off);
    }
    if (act && q == 0) {
      float* bn1 = ws + BN1_OFF + (size_t)(blockIdx.x & 31) * 58;
      atomicAdd(&bn1[n*2+0], s1);
      atomicAdd(&bn1[n*2+1], s2);
    }
  }
  __syncthreads();

  const int wv = tid >> 6, lane = tid & 63;
  const int lrow = lane & 15, quad = lane >> 4;
  const int bb = wv >> 2;
  const int n0 = (wv & 3) * 32;
  const unsigned short* imgp = (const unsigned short*)(ws + IMG_OFF);
  const unsigned short* gB0 = imgp + (size_t)(n0 + lrow)*448 + quad*8;
  const unsigned short* gB1 = gB0 + 16*448;
  const unsigned short* tA = t_s + (size_t)(bb*32)*TSTR + quad*8;

  f32x4 a00 = (f32x4){0.f,0.f,0.f,0.f}, a01 = a00, a10 = a00, a11 = a00;
  bf16x8 Bc0 = *(const bf16x8*)(gB0);
  bf16x8 Bc1 = *(const bf16x8*)(gB1);
  #pragma unroll
  for (int ks = 0; ks < 14; ++ks) {
    bf16x8 Bn0, Bn1;
    if (ks < 13) {
      Bn0 = *(const bf16x8*)(gB0 + (ks+1)*32);
      Bn1 = *(const bf16x8*)(gB1 + (ks+1)*32);
    }
    bf16x8 A0 = *(const bf16x8*)(tA + lrow*TSTR + ks*32);
    bf16x8 A1 = *(const bf16x8*)(tA + (16+lrow)*TSTR + ks*32);
    a00 = __builtin_amdgcn_mfma_f32_16x16x32_bf16(A0, Bc0, a00, 0, 0, 0);
    a01 = __builtin_amdgcn_mfma_f32_16x16x32_bf16(A0, Bc1, a01, 0, 0, 0);
    a10 = __builtin_amdgcn_mfma_f32_16x16x32_bf16(A1, Bc0, a10, 0, 0, 0);
    a11 = __builtin_amdgcn_mfma_f32_16x16x32_bf16(A1, Bc1, a11, 0, 0, 0);
    Bc0 = Bn0; Bc1 = Bn1;
  }
  __syncthreads();

  {
    unsigned short* ut = t_s + bb*4352;
    const int fb0 = n0 + lrow, fb1 = n0 + 16 + lrow;
    #pragma unroll
    for (int i = 0; i < 4; ++i) {
      int m0 = quad*4 + i, m1 = 16 + quad*4 + i;
      ut[fb0*UTILS + m0] = f2bf(a00[i]);
      ut[fb1*UTILS + m0] = f2bf(a01[i]);
      ut[fb0*UTILS + m1] = f2bf(a10[i]);
      ut[fb1*UTILS + m1] = f2bf(a11[i]);
    }
  }
  __syncthreads();
  {
    const unsigned* u32t = (const unsigned*)t_s;
    unsigned short* ws16 = (unsigned short*)ws;
    #pragma unroll
    for (int it = 0; it < 8; ++it) {
      int idx = tid + it*512;
      int bbs = idx >> 11, rem = idx & 2047;
      int f = rem >> 4, pr = rem & 15;
      unsigned* Ug = (unsigned*)(ws16 + (size_t)(b0 + bbs)*UTSTR);
      Ug[f*16 + pr] = u32t[bbs*2176 + f*17 + pr];
    }
  }
}

/* K3 v2: barrier-free. One wave owns one b (wave-private LDS A-matrix).
   256 thr = 4 waves; each wave does 4 consecutive b's; grid 512 -> all waves co-resident. */
__global__ __launch_bounds__(256, 2) void k3_gnn(
    const float* __restrict__ corr, const float* __restrict__ bg,
    const float* __restrict__ agnn, float* __restrict__ ws)
{
  __shared__ unsigned short a_all[4*1280];   /* per wave: 32x40 bf16 */

  const int tid = threadIdx.x;
  const int wv = tid >> 6, lane = tid & 63;
  const int lrow = lane & 15, quad = lane >> 4;
  unsigned short* as = a_all + wv*1280;

  /* bn1 finalize per wave (L2-hot), lane-indexed registers */
  const int ln = (lane < 29) ? lane : 0;
  float m1r, is1r;
  {
    float s1 = 0.f, s2 = 0.f;
    #pragma unroll 8
    for (int s = 0; s < 32; ++s) {
      s1 += ws[BN1_OFF + s*58 + ln*2 + 0];
      s2 += ws[BN1_OFF + s*58 + ln*2 + 1];
    }
    const float inv = 1.f / (float)(B_ * DC);
    float mean = s1 * inv;
    float var  = s2 * inv - mean * mean;
    m1r = mean; is1r = rsqrtf(var + EPSBN);
  }

  /* per-lane epilogue constants for f = ft*16 + lrow */
  float vc[8], csc[8], bgc[8];
  #pragma unroll
  for (int ft = 0; ft < 8; ++ft) {
    int f = ft*16 + lrow;
    vc[ft]  = ws[V_OFF + f];
    csc[ft] = ws[CSW_OFF + f];
    bgc[ft] = bg[f];
  }
  const float ag = agnn[0];

  const int b0 = blockIdx.x*16 + wv*4;
  for (int bb = 0; bb < 4; ++bb) {
    const int b = b0 + bb;
    unsigned short* Utb = (unsigned short*)ws + (size_t)b * UTSTR;
    const float* cb = corr + (size_t)b * 841;

    /* B-frags: whole Ut[b] (32 m x 128 f) */
    bf16x8 Bf[8];
    #pragma unroll
    for (int ft = 0; ft < 8; ++ft)
      Bf[ft] = *(const bf16x8*)&Utb[(size_t)(ft*16 + lrow)*32 + quad*8];

    /* corr -> scaled bf16 A in wave-private LDS */
    float cval[14];
    #pragma unroll
    for (int j = 0; j < 14; ++j)
      cval[j] = cb[min(lane + j*64, 840)];
    #pragma unroll
    for (int j = 0; j < 14; ++j) {
      int i = lane + j*64;
      if (i < 841) {
        unsigned n = ((unsigned)i * 565u) >> 14;
        unsigned m = (unsigned)i - n*29u;
        float is1m = __shfl(is1r, (int)m);
        as[n*40 + m] = f2bf(cval[j] * is1m);
      }
    }
    if (lane < 29) {            /* zero K-pad m=29..31 */
      as[lane*40 + 29] = 0;
      as[lane*40 + 30] = 0;
      as[lane*40 + 31] = 0;
    }

    /* cms[n] for n=lane<29 (wave-internal lgkmcnt ordering; no barrier) */
    float cm = 0.f;
    #pragma unroll
    for (int m = 0; m < 29; ++m) {
      float a = bf2f(as[ln*40 + m]);
      cm = fmaf(a, __shfl(m1r, m), cm);
    }

    /* MFMA: 2 m-tiles x 8 f-tiles */
    bf16x8 A0 = *(const bf16x8*)&as[lrow*40 + quad*8];
    bf16x8 A1 = *(const bf16x8*)&as[(16 + lrow)*40 + quad*8];
    f32x4 acc[2][8];
    #pragma unroll
    for (int ft = 0; ft < 8; ++ft) {
      acc[0][ft] = (f32x4){0.f,0.f,0.f,0.f};
      acc[1][ft] = (f32x4){0.f,0.f,0.f,0.f};
      acc[0][ft] = __builtin_amdgcn_mfma_f32_16x16x32_bf16(A0, Bf[ft], acc[0][ft], 0, 0, 0);
      acc[1][ft] = __builtin_amdgcn_mfma_f32_16x16x32_bf16(A1, Bf[ft], acc[1][ft], 0, 0, 0);
    }

    /* epilogue: y1 stores (n<29), rowstats, bn2 atomics */
    float* rs = (float*)(Utb + RS_SH);
    float* bn2 = ws + BN2_OFF + (size_t)(b & 31) * 58;
    #pragma unroll
    for (int mt = 0; mt < 2; ++mt) {
      #pragma unroll
      for (int i = 0; i < 4; ++i) {
        int n = mt*16 + quad*4 + i;
        bool valid = (n < 29);
        float cmn = __shfl(cm, valid ? n : 28);
        float sy = 0.f, sy2 = 0.f, sv = 0.f;
        #pragma unroll
        for (int ft = 0; ft < 8; ++ft) {
          float y = acc[mt][ft][i] - cmn*csc[ft] + bgc[ft];
          y = (y >= 0.f) ? y : ag*y;
          if (valid) Utb[n*D_ + ft*16 + lrow] = f2bf(y);
          sy += y; sy2 = fmaf(y, y, sy2); sv = fmaf(y, vc[ft], sv);
        }
        #pragma unroll
        for (int off = 8; off >= 1; off >>= 1) {
          sy  += __shfl_xor(sy, off);
          sy2 += __shfl_xor(sy2, off);
          sv  += __shfl_xor(sv, off);
        }
        if (valid && lrow == 0) {
          rs[n]      = sy;
          rs[29 + n] = sy2;
          rs[58 + n] = sv;
          atomicAdd(&bn2[n*2+0], sy);
          atomicAdd(&bn2[n*2+1], sy2);
        }
      }
    }
  }
}

/* K4: 32 b per block (unchanged from r6). */
__global__ __launch_bounds__(256) void k4_pool(
    const float* __restrict__ bpv, float* __restrict__ ws)
{
  __shared__ unsigned short Atile[32*ATSTR];
  __shared__ float m2s[29], is2s[29], koffs[32];
  const int tid = threadIdx.x, wv = tid >> 6, lane = tid & 63;
  const int b0 = blockIdx.x * 32;
  const unsigned short* U16 = (const unsigned short*)ws;

  if (tid < 29) {
    float s1 = 0.f, s2 = 0.f;
    #pragma unroll 4
    for (int s = 0; s < 32; ++s) {
      s1 += ws[BN2_OFF + s*58 + tid*2 + 0];
      s2 += ws[BN2_OFF + s*58 + tid*2 + 1];
    }
    const float inv = 1.f / (float)(B_ * D_);
    float mean = s1 * inv, var = s2 * inv - mean * mean;
    m2s[tid] = mean; is2s[tid] = rsqrtf(var + EPSBN);
  }
  __syncthreads();

  const float V1 = ws[V1_OFF];
  unsigned* At32 = (unsigned*)Atile;
  for (int mb = 0; mb < 8; ++mb) {
    const int m = wv*8 + mb;
    const unsigned short* yb = U16 + (size_t)(b0 + m) * UTSTR;
    const float* rs = (const float*)(yb + RS_SH);
    float agg = -1e30f, m2 = 0.f, is2 = 0.f;
    if (lane < 29) {
      float S1 = rs[lane], S2 = rs[29+lane], Sv = rs[58+lane];
      m2 = m2s[lane]; is2 = is2s[lane];
      float ss = fmaxf(S2 - 2.f*m2*S1 + 128.f*m2*m2, 0.f);
      agg = (is2*(Sv - m2*V1)) / (is2*sqrtf(ss) + 1e-8f);
    }
    float mx = agg;
    #pragma unroll
    for (int off = 32; off >= 1; off >>= 1) mx = fmaxf(mx, __shfl_xor(mx, off));
    float e = (lane < 29) ? __expf(agg - mx) : 0.f;
    float den = e, kof = e*is2*m2;
    #pragma unroll
    for (int off = 32; off >= 1; off >>= 1) { den += __shfl_xor(den, off); kof += __shfl_xor(kof, off); }
    float rden = 1.f / den;
    float c = e * is2 * rden;
    if (lane == 0) koffs[m] = kof * rden;
    const unsigned* y32 = (const unsigned*)yb;
    float p0 = 0.f, p1 = 0.f;
    #pragma unroll
    for (int n = 0; n < 29; ++n) {
      float cn = __shfl(c, n);
      unsigned u = y32[n*64 + lane];
      p0 = fmaf(cn, bf2f(u & 0xffffu), p0);
      p1 = fmaf(cn, bf2f(u >> 16), p1);
    }
    At32[m*68 + lane] = (unsigned)f2bf(p0) | ((unsigned)f2bf(p1) << 16);
  }
  __syncthreads();

  const int lrow = lane & 15, quad = lane >> 4;
  const int n0 = wv * 32;
  const unsigned short* wpi = (const unsigned short*)(ws + WPI_OFF);
  f32x4 acc[2][2];
  acc[0][0] = (f32x4){0.f,0.f,0.f,0.f}; acc[0][1] = acc[0][0];
  acc[1][0] = acc[0][0]; acc[1][1] = acc[0][0];
  #pragma unroll
  for (int ks = 0; ks < 4; ++ks) {
    bf16x8 A0 = *(const bf16x8*)&Atile[lrow*ATSTR + ks*32 + quad*8];
    bf16x8 A1 = *(const bf16x8*)&Atile[(16+lrow)*ATSTR + ks*32 + quad*8];
    bf16x8 Bq0 = *(const bf16x8*)&wpi[(size_t)(n0 + lrow)*128 + ks*32 + quad*8];
    bf16x8 Bq1 = *(const bf16x8*)&wpi[(size_t)(n0 + 16 + lrow)*128 + ks*32 + quad*8];
    acc[0][0] = __builtin_amdgcn_mfma_f32_16x16x32_bf16(A0, Bq0, acc[0][0], 0, 0, 0);
    acc[0][1] = __builtin_amdgcn_mfma_f32_16x16x32_bf16(A0, Bq1, acc[0][1], 0, 0, 0);
    acc[1][0] = __builtin_amdgcn_mfma_f32_16x16x32_bf16(A1, Bq0, acc[1][0], 0, 0, 0);
    acc[1][1] = __builtin_amdgcn_mfma_f32_16x16x32_bf16(A1, Bq1, acc[1][1], 0, 0, 0);
  }

  float* bn3 = ws + BN3_OFF + (size_t)(blockIdx.x & 31) * 256;
  #pragma unroll
  for (int nt = 0; nt < 2; ++nt) {
    int col = n0 + nt*16 + lrow;
    float cswp = ws[CSWP_OFF + col], bp = bpv[col];
    float s1c = 0.f, s2c = 0.f;
    #pragma unroll
    for (int mt = 0; mt < 2; ++mt) {
      #pragma unroll
      for (int i = 0; i < 4; ++i) {
        int m = mt*16 + quad*4 + i;
        float x3 = acc[mt][nt][i] - koffs[m]*cswp + bp;
        ws[X3_OFF + (size_t)(b0 + m)*D_ + col] = x3;
        s1c += x3; s2c = fmaf(x3, x3, s2c);
      }
    }
    s1c += __shfl_xor(s1c, 16); s1c += __shfl_xor(s1c, 32);
    s2c += __shfl_xor(s2c, 16); s2c += __shfl_xor(s2c, 32);
    if (quad == 0) {
      atomicAdd(&bn3[col*2+0], s1c);
      atomicAdd(&bn3[col*2+1], s2c);
    }
  }
}

/* K5: 32 b per block (unchanged from r6). */
__global__ __launch_bounds__(256) void k5_mlp(
    const float* __restrict__ bm1, const float* __restrict__ amlp,
    const float* __restrict__ Wm2, const float* __restrict__ bm2,
    float* __restrict__ ws, float* __restrict__ out)
{
  __shared__ unsigned short Atile[32*ATSTR];
  __shared__ float m3s[128], is3s[128], logit_s[32];
  const int tid = threadIdx.x, wv = tid >> 6, lane = tid & 63;
  const int b0 = blockIdx.x * 32;

  if (tid < 128) {
    float s1 = 0.f, s2 = 0.f;
    #pragma unroll 4
    for (int s = 0; s < 32; ++s) {
      s1 += ws[BN3_OFF + s*256 + tid*2 + 0];
      s2 += ws[BN3_OFF + s*256 + tid*2 + 1];
    }
    const float inv = 1.f / (float)B_;
    float mean = s1 * inv, var = s2 * inv - mean * mean;
    m3s[tid] = mean; is3s[tid] = rsqrtf(var + EPSBN);
  }
  if (tid >= 128 && tid < 160) logit_s[tid-128] = 0.f;
  __syncthreads();

  for (int it = 0; it < 16; ++it) {
    int idx = tid + it*256;
    int row = idx >> 7, col = idx & 127;
    float v = (ws[X3_OFF + (size_t)(b0+row)*D_ + col] - m3s[col]) * is3s[col];
    Atile[row*ATSTR + col] = f2bf(v);
  }
  __syncthreads();

  const int lrow = lane & 15, quad = lane >> 4;
  const int n0 = wv * 32;
  const unsigned short* wmi = (const unsigned short*)(ws + WM1I_OFF);
  f32x4 acc[2][2];
  acc[0][0] = (f32x4){0.f,0.f,0.f,0.f}; acc[0][1] = acc[0][0];
  acc[1][0] = acc[0][0]; acc[1][1] = acc[0][0];
  #pragma unroll
  for (int ks = 0; ks < 4; ++ks) {
    bf16x8 A0 = *(const bf16x8*)&Atile[lrow*ATSTR + ks*32 + quad*8];
    bf16x8 A1 = *(const bf16x8*)&Atile[(16+lrow)*ATSTR + ks*32 + quad*8];
    bf16x8 Bq0 = *(const bf16x8*)&wmi[(size_t)(n0 + lrow)*128 + ks*32 + quad*8];
    bf16x8 Bq1 = *(const bf16x8*)&wmi[(size_t)(n0 + 16 + lrow)*128 + ks*32 + quad*8];
    acc[0][0] = __builtin_amdgcn_mfma_f32_16x16x32_bf16(A0, Bq0, acc[0][0], 0, 0, 0);
    acc[0][1] = __builtin_amdgcn_mfma_f32_16x16x32_bf16(A0, Bq1, acc[0][1], 0, 0, 0);
    acc[1][0] = __builtin_amdgcn_mfma_f32_16x16x32_bf16(A1, Bq0, acc[1][0], 0, 0, 0);
    acc[1][1] = __builtin_amdgcn_mfma_f32_16x16x32_bf16(A1, Bq1, acc[1][1], 0, 0, 0);
  }

  const float am = amlp[0];
  float bmc[2], wm2c[2];
  #pragma unroll
  for (int nt = 0; nt < 2; ++nt) {
    int col = n0 + nt*16 + lrow;
    bmc[nt] = bm1[col]; wm2c[nt] = Wm2[col];
  }
  #pragma unroll
  for (int mt = 0; mt < 2; ++mt) {
    #pragma unroll
    for (int i = 0; i < 4; ++i) {
      float pm = 0.f;
      #pragma unroll
      for (int nt = 0; nt < 2; ++nt) {
        float h = acc[mt][nt][i] + bmc[nt];
        h = (h >= 0.f) ? h : am*h;
        pm = fmaf(h, wm2c[nt], pm);
      }
      #pragma unroll
      for (int off = 8; off >= 1; off >>= 1) pm += __shfl_xor(pm, off);
      if (lrow == 0) atomicAdd(&logit_s[mt*16 + quad*4 + i], pm);
    }
  }
  __syncthreads();
  if (tid < 32) {
    float logit = logit_s[tid] + bm2[0];
    out[b0 + tid] = 1.f / (1.f + expf(-logit));
  }
}

extern "C" void kernel_launch(void* const* d_in, const int* in_sizes, int n_in,
                              void* d_out, int out_size, void* d_ws, size_t ws_size,
                              hipStream_t stream)
{
  (void)in_sizes; (void)n_in; (void)out_size; (void)ws_size;
  const float* X    = (const float*)d_in[0];
  const float* corr = (const float*)d_in[1];
  const float* wc1  = (const float*)d_in[2];
  const float* bc1  = (const float*)d_in[3];
  const float* wc2  = (const float*)d_in[4];
  const float* bc2  = (const float*)d_in[5];
  const float* wc3  = (const float*)d_in[6];
  const float* bc3  = (const float*)d_in[7];
  const float* acnn = (const float*)d_in[8];
  const float* Wg   = (const float*)d_in[9];
  const float* bg   = (const float*)d_in[10];
  const float* agnn = (const float*)d_in[11];
  const float* cent = (const float*)d_in[12];
  const float* hw   = (const float*)d_in[13];
  const float* Wp   = (const float*)d_in[14];
  const float* bp   = (const float*)d_in[15];
  const float* Wm1  = (const float*)d_in[16];
  const float* bm1  = (const float*)d_in[17];
  const float* amlp = (const float*)d_in[18];
  const float* Wm2  = (const float*)d_in[19];
  const float* bm2  = (const float*)d_in[20];
  float* ws  = (float*)d_ws;
  float* out = (float*)d_out;

  hipMemsetAsync(ws + ACC_OFF, 0, 11904 * sizeof(float), stream);
  k0a_img<<<18, 256, 0, stream>>>(Wg, Wp, Wm1, ws);
  k0b_cent<<<1, 128, 0, stream>>>(cent, hw, ws);
  k1_conv_gemm<<<B_/2, 512, 0, stream>>>(X, wc1, bc1, wc2, bc2, wc3, bc3, acnn, ws);
  k3_gnn<<<B_/16, 256, 0, stream>>>(corr, bg, agnn, ws);
  k4_pool<<<B_/32, 256, 0, stream>>>(bp, ws);
  k5_mlp<<<B_/32, 256, 0, stream>>>(bm1, amlp, Wm2, bm2, ws, out);
}